// Round 2
// baseline (118.269 us; speedup 1.0000x reference)
//
#include <hip/hip_runtime.h>
#include <math.h>

#define IH 512
#define IW 512
#define NPX (IH*IW)
#define TS 32
#define YHALO 7              // 5 (search) + 2 (patch)
#define RHALO 5              // search only
#define YD (TS + 2*YHALO)    // 46
#define RD (TS + 2*RHALO)    // 42
#define NSLICE 4

// ---------------- split compute kernel: one dx-group per blockIdx.z ----------
__global__ __launch_bounds__(256, 4)
void nlm_part(const float* __restrict__ rgb,
              const float* __restrict__ sigma,
              float4* __restrict__ ws) {
    __shared__ float Y[YD * YD];
    __shared__ float RL[RD * RD], GL[RD * RD], BL[RD * RD];

    const int tid = threadIdx.x;
    const int tx0 = blockIdx.x * TS;
    const int ty0 = blockIdx.y * TS;
    const int slice = blockIdx.z;

    const float* Rp = rgb;
    const float* Gp = rgb + NPX;
    const float* Bp = rgb + 2 * NPX;

    for (int idx = tid; idx < YD * YD; idx += 256) {
        int a = idx / YD, b = idx - a * YD;
        int gy = (ty0 + a - YHALO) & (IH - 1);
        int gx = (tx0 + b - YHALO) & (IW - 1);
        int g = gy * IW + gx;
        Y[idx] = 0.299f * Rp[g] + 0.587f * Gp[g] + 0.114f * Bp[g];
    }
    for (int idx = tid; idx < RD * RD; idx += 256) {
        int a = idx / RD, b = idx - a * RD;
        int gy = (ty0 + a - RHALO) & (IH - 1);
        int gx = (tx0 + b - RHALO) & (IW - 1);
        int g = gy * IW + gx;
        RL[idx] = Rp[g];
        GL[idx] = Gp[g];
        BL[idx] = Bp[g];
    }
    __syncthreads();

    const float inv_h = 1.0f / (fmaxf(sigma[0] * 2.0f, 0.0f) + 1e-6f);

    const int tx = tid & 31;   // column within tile
    const int tz = tid >> 5;   // row strip 0..7
    const int r0 = tz * 4;     // first output row of this strip (tile coords)

    // flat LDS base indices for this thread
    const int ybase0 = (YHALO + r0 - 2) * YD + (YHALO + tx - 2);
    const int rbase0 = (RHALO + r0) * RD + (RHALO + tx);

    // cache base-Y patch: rows r0-2 .. r0+5, cols tx-2 .. tx+2
    float yb[8][5];
    #pragma unroll
    for (int i = 0; i < 8; ++i)
        #pragma unroll
        for (int b = 0; b < 5; ++b)
            yb[i][b] = Y[ybase0 + i * YD + b];

    float accR[4] = {0.f, 0.f, 0.f, 0.f};
    float accG[4] = {0.f, 0.f, 0.f, 0.f};
    float accB[4] = {0.f, 0.f, 0.f, 0.f};
    float den[4]  = {0.f, 0.f, 0.f, 0.f};

    const int dxlo  = (slice < 3) ? (-5 + 3 * slice) : 4;
    const int dxcnt = (slice < 3) ? 3 : 2;

    for (int u = 0; u < dxcnt; ++u) {
        const int dx  = dxlo + u;
        const int yb2 = ybase0 - dx;   // column shift folded into base
        const int rb2 = rbase0 - dx;
        #pragma unroll
        for (int dy = -5; dy <= 5; ++dy) {
            // horizontal 5-tap squared-diff sums for the 8 rows of this strip
            float hs[8];
            #pragma unroll
            for (int i = 0; i < 8; ++i) {
                float s = 0.f;
                #pragma unroll
                for (int b = 0; b < 5; ++b) {
                    float ys = Y[yb2 + (i - dy) * YD + b];
                    float d = yb[i][b] - ys;
                    s = fmaf(d, d, s);
                }
                hs[i] = s;
            }
            // vertical box via prefix sums
            float pre[9];
            pre[0] = 0.f;
            #pragma unroll
            for (int i = 0; i < 8; ++i) pre[i + 1] = pre[i] + hs[i];
            #pragma unroll
            for (int rr = 0; rr < 4; ++rr) {
                float box = pre[rr + 5] - pre[rr];
                float w = __expf(-sqrtf(box) * inv_h);
                int s2 = rb2 + (rr - dy) * RD;
                accR[rr] = fmaf(w, RL[s2], accR[rr]);
                accG[rr] = fmaf(w, GL[s2], accG[rr]);
                accB[rr] = fmaf(w, BL[s2], accB[rr]);
                den[rr] += w;
            }
        }
    }

    #pragma unroll
    for (int rr = 0; rr < 4; ++rr) {
        int px = (ty0 + r0 + rr) * IW + tx0 + tx;
        ws[(size_t)slice * NPX + px] =
            make_float4(accR[rr], accG[rr], accB[rr], den[rr]);
    }
}

// ---------------- combine: sum 4 slices, normalize, clip ---------------------
__global__ __launch_bounds__(256)
void nlm_combine(const float4* __restrict__ ws, float* __restrict__ out) {
    int px = blockIdx.x * 256 + threadIdx.x;
    float4 a = ws[px];
    float4 b = ws[NPX + px];
    float4 c = ws[2 * (size_t)NPX + px];
    float4 d = ws[3 * (size_t)NPX + px];
    float r  = a.x + b.x + c.x + d.x;
    float g  = a.y + b.y + c.y + d.y;
    float bl = a.z + b.z + c.z + d.z;
    float w  = a.w + b.w + c.w + d.w;
    float iw = 1.0f / w;
    out[px]               = fminf(fmaxf(r  * iw, 0.f), 1.f);
    out[NPX + px]         = fminf(fmaxf(g  * iw, 0.f), 1.f);
    out[2 * NPX + px]     = fminf(fmaxf(bl * iw, 0.f), 1.f);
}

// ---------------- fallback: original monolithic kernel -----------------------
__global__ __launch_bounds__(256)
void nlm_mono(const float* __restrict__ rgb,
              const float* __restrict__ sigma,
              float* __restrict__ out) {
    __shared__ float Y[YD * YD];
    __shared__ float RL[RD * RD], GL[RD * RD], BL[RD * RD];

    const int tid = threadIdx.x;
    const int tx0 = blockIdx.x * TS;
    const int ty0 = blockIdx.y * TS;

    const float* Rp = rgb;
    const float* Gp = rgb + NPX;
    const float* Bp = rgb + 2 * NPX;

    for (int idx = tid; idx < YD * YD; idx += 256) {
        int a = idx / YD, b = idx - a * YD;
        int gy = (ty0 + a - YHALO) & (IH - 1);
        int gx = (tx0 + b - YHALO) & (IW - 1);
        int g = gy * IW + gx;
        Y[idx] = 0.299f * Rp[g] + 0.587f * Gp[g] + 0.114f * Bp[g];
    }
    for (int idx = tid; idx < RD * RD; idx += 256) {
        int a = idx / RD, b = idx - a * RD;
        int gy = (ty0 + a - RHALO) & (IH - 1);
        int gx = (tx0 + b - RHALO) & (IW - 1);
        int g = gy * IW + gx;
        RL[idx] = Rp[g];
        GL[idx] = Gp[g];
        BL[idx] = Bp[g];
    }
    __syncthreads();

    const float inv_h = 1.0f / (fmaxf(sigma[0] * 2.0f, 0.0f) + 1e-6f);
    const int tx = tid & 31;
    const int tz = tid >> 5;
    const int r0 = tz * 4;
    const int ybase0 = (YHALO + r0 - 2) * YD + (YHALO + tx - 2);
    const int rbase0 = (RHALO + r0) * RD + (RHALO + tx);

    float yb[8][5];
    #pragma unroll
    for (int i = 0; i < 8; ++i)
        #pragma unroll
        for (int b = 0; b < 5; ++b)
            yb[i][b] = Y[ybase0 + i * YD + b];

    float accR[4] = {0.f,0.f,0.f,0.f}, accG[4] = {0.f,0.f,0.f,0.f};
    float accB[4] = {0.f,0.f,0.f,0.f}, den[4] = {0.f,0.f,0.f,0.f};

    for (int dx = -5; dx <= 5; ++dx) {
        const int yb2 = ybase0 - dx;
        const int rb2 = rbase0 - dx;
        #pragma unroll
        for (int dy = -5; dy <= 5; ++dy) {
            float hs[8];
            #pragma unroll
            for (int i = 0; i < 8; ++i) {
                float s = 0.f;
                #pragma unroll
                for (int b = 0; b < 5; ++b) {
                    float ys = Y[yb2 + (i - dy) * YD + b];
                    float d = yb[i][b] - ys;
                    s = fmaf(d, d, s);
                }
                hs[i] = s;
            }
            float pre[9];
            pre[0] = 0.f;
            #pragma unroll
            for (int i = 0; i < 8; ++i) pre[i + 1] = pre[i] + hs[i];
            #pragma unroll
            for (int rr = 0; rr < 4; ++rr) {
                float box = pre[rr + 5] - pre[rr];
                float w = __expf(-sqrtf(box) * inv_h);
                int s2 = rb2 + (rr - dy) * RD;
                accR[rr] = fmaf(w, RL[s2], accR[rr]);
                accG[rr] = fmaf(w, GL[s2], accG[rr]);
                accB[rr] = fmaf(w, BL[s2], accB[rr]);
                den[rr] += w;
            }
        }
    }

    #pragma unroll
    for (int rr = 0; rr < 4; ++rr) {
        int px = (ty0 + r0 + rr) * IW + tx0 + tx;
        float iw = 1.0f / den[rr];
        out[px]           = fminf(fmaxf(accR[rr] * iw, 0.f), 1.f);
        out[NPX + px]     = fminf(fmaxf(accG[rr] * iw, 0.f), 1.f);
        out[2 * NPX + px] = fminf(fmaxf(accB[rr] * iw, 0.f), 1.f);
    }
}

extern "C" void kernel_launch(void* const* d_in, const int* in_sizes, int n_in,
                              void* d_out, int out_size, void* d_ws, size_t ws_size,
                              hipStream_t stream) {
    const float* rgb   = (const float*)d_in[0];
    const float* sigma = (const float*)d_in[1];
    float* out = (float*)d_out;

    const size_t need = (size_t)NSLICE * NPX * sizeof(float4);
    if (ws_size >= need) {
        float4* ws = (float4*)d_ws;
        dim3 grid(IW / TS, IH / TS, NSLICE);   // 16 x 16 x 4 = 1024 blocks
        nlm_part<<<grid, dim3(256), 0, stream>>>(rgb, sigma, ws);
        nlm_combine<<<dim3(NPX / 256), dim3(256), 0, stream>>>(ws, out);
    } else {
        dim3 grid(IW / TS, IH / TS);
        nlm_mono<<<grid, dim3(256), 0, stream>>>(rgb, sigma, out);
    }
}

// Round 3
// 56.356 us; speedup vs baseline: 2.0986x; 2.0986x over previous
//
#include <hip/hip_runtime.h>
#include <math.h>

#define IH 512
#define IW 512
#define NPX (IH*IW)
#define TS 32
#define YHALO 7              // 5 (search) + 2 (patch)
#define RHALO 5              // search only
#define YD (TS + 2*YHALO)    // 46
#define RD (TS + 2*RHALO)    // 42
#define NSLICE 4

// ---------------- split compute kernel: one dx-group per blockIdx.z ----------
// NOTE: no min-waves clamp! __launch_bounds__(256,4) forced VGPR=64 and spilled
// ~0.5 GB/dispatch to scratch (round-2 post-mortem). 104 VGPRs already gives
// 4 waves/SIMD; LDS (29.7 KB) allows 4 blocks/CU for the 1024-block grid.
__global__ __launch_bounds__(256)
void nlm_part(const float* __restrict__ rgb,
              const float* __restrict__ sigma,
              float4* __restrict__ ws) {
    __shared__ float Y[YD * YD];
    __shared__ float RL[RD * RD], GL[RD * RD], BL[RD * RD];

    const int tid = threadIdx.x;
    const int tx0 = blockIdx.x * TS;
    const int ty0 = blockIdx.y * TS;
    const int slice = blockIdx.z;

    const float* Rp = rgb;
    const float* Gp = rgb + NPX;
    const float* Bp = rgb + 2 * NPX;

    for (int idx = tid; idx < YD * YD; idx += 256) {
        int a = idx / YD, b = idx - a * YD;
        int gy = (ty0 + a - YHALO) & (IH - 1);
        int gx = (tx0 + b - YHALO) & (IW - 1);
        int g = gy * IW + gx;
        Y[idx] = 0.299f * Rp[g] + 0.587f * Gp[g] + 0.114f * Bp[g];
    }
    for (int idx = tid; idx < RD * RD; idx += 256) {
        int a = idx / RD, b = idx - a * RD;
        int gy = (ty0 + a - RHALO) & (IH - 1);
        int gx = (tx0 + b - RHALO) & (IW - 1);
        int g = gy * IW + gx;
        RL[idx] = Rp[g];
        GL[idx] = Gp[g];
        BL[idx] = Bp[g];
    }
    __syncthreads();

    const float inv_h = 1.0f / (fmaxf(sigma[0] * 2.0f, 0.0f) + 1e-6f);

    const int tx = tid & 31;   // column within tile
    const int tz = tid >> 5;   // row strip 0..7
    const int r0 = tz * 4;     // first output row of this strip (tile coords)

    const int ybase0 = (YHALO + r0 - 2) * YD + (YHALO + tx - 2);
    const int rbase0 = (RHALO + r0) * RD + (RHALO + tx);

    // cache base-Y patch: rows r0-2 .. r0+5, cols tx-2 .. tx+2
    float yb[8][5];
    #pragma unroll
    for (int i = 0; i < 8; ++i)
        #pragma unroll
        for (int b = 0; b < 5; ++b)
            yb[i][b] = Y[ybase0 + i * YD + b];

    float accR[4] = {0.f, 0.f, 0.f, 0.f};
    float accG[4] = {0.f, 0.f, 0.f, 0.f};
    float accB[4] = {0.f, 0.f, 0.f, 0.f};
    float den[4]  = {0.f, 0.f, 0.f, 0.f};

    const int dxlo  = (slice < 3) ? (-5 + 3 * slice) : 4;
    const int dxcnt = (slice < 3) ? 3 : 2;

    for (int u = 0; u < dxcnt; ++u) {
        const int dx  = dxlo + u;
        const int yb2 = ybase0 - dx;   // column shift folded into base
        const int rb2 = rbase0 - dx;
        #pragma unroll
        for (int dy = -5; dy <= 5; ++dy) {
            // horizontal 5-tap squared-diff sums for the 8 rows of this strip
            float hs[8];
            #pragma unroll
            for (int i = 0; i < 8; ++i) {
                float s = 0.f;
                #pragma unroll
                for (int b = 0; b < 5; ++b) {
                    float ys = Y[yb2 + (i - dy) * YD + b];
                    float d = yb[i][b] - ys;
                    s = fmaf(d, d, s);
                }
                hs[i] = s;
            }
            // vertical box via prefix sums
            float pre[9];
            pre[0] = 0.f;
            #pragma unroll
            for (int i = 0; i < 8; ++i) pre[i + 1] = pre[i] + hs[i];
            #pragma unroll
            for (int rr = 0; rr < 4; ++rr) {
                float box = pre[rr + 5] - pre[rr];
                float w = __expf(-sqrtf(box) * inv_h);
                int s2 = rb2 + (rr - dy) * RD;
                accR[rr] = fmaf(w, RL[s2], accR[rr]);
                accG[rr] = fmaf(w, GL[s2], accG[rr]);
                accB[rr] = fmaf(w, BL[s2], accB[rr]);
                den[rr] += w;
            }
        }
    }

    #pragma unroll
    for (int rr = 0; rr < 4; ++rr) {
        int px = (ty0 + r0 + rr) * IW + tx0 + tx;
        ws[(size_t)slice * NPX + px] =
            make_float4(accR[rr], accG[rr], accB[rr], den[rr]);
    }
}

// ---------------- combine: sum 4 slices, normalize, clip ---------------------
__global__ __launch_bounds__(256)
void nlm_combine(const float4* __restrict__ ws, float* __restrict__ out) {
    int px = blockIdx.x * 256 + threadIdx.x;
    float4 a = ws[px];
    float4 b = ws[NPX + px];
    float4 c = ws[2 * (size_t)NPX + px];
    float4 d = ws[3 * (size_t)NPX + px];
    float r  = a.x + b.x + c.x + d.x;
    float g  = a.y + b.y + c.y + d.y;
    float bl = a.z + b.z + c.z + d.z;
    float w  = a.w + b.w + c.w + d.w;
    float iw = 1.0f / w;
    out[px]               = fminf(fmaxf(r  * iw, 0.f), 1.f);
    out[NPX + px]         = fminf(fmaxf(g  * iw, 0.f), 1.f);
    out[2 * NPX + px]     = fminf(fmaxf(bl * iw, 0.f), 1.f);
}

// ---------------- fallback: original monolithic kernel -----------------------
__global__ __launch_bounds__(256)
void nlm_mono(const float* __restrict__ rgb,
              const float* __restrict__ sigma,
              float* __restrict__ out) {
    __shared__ float Y[YD * YD];
    __shared__ float RL[RD * RD], GL[RD * RD], BL[RD * RD];

    const int tid = threadIdx.x;
    const int tx0 = blockIdx.x * TS;
    const int ty0 = blockIdx.y * TS;

    const float* Rp = rgb;
    const float* Gp = rgb + NPX;
    const float* Bp = rgb + 2 * NPX;

    for (int idx = tid; idx < YD * YD; idx += 256) {
        int a = idx / YD, b = idx - a * YD;
        int gy = (ty0 + a - YHALO) & (IH - 1);
        int gx = (tx0 + b - YHALO) & (IW - 1);
        int g = gy * IW + gx;
        Y[idx] = 0.299f * Rp[g] + 0.587f * Gp[g] + 0.114f * Bp[g];
    }
    for (int idx = tid; idx < RD * RD; idx += 256) {
        int a = idx / RD, b = idx - a * RD;
        int gy = (ty0 + a - RHALO) & (IH - 1);
        int gx = (tx0 + b - RHALO) & (IW - 1);
        int g = gy * IW + gx;
        RL[idx] = Rp[g];
        GL[idx] = Gp[g];
        BL[idx] = Bp[g];
    }
    __syncthreads();

    const float inv_h = 1.0f / (fmaxf(sigma[0] * 2.0f, 0.0f) + 1e-6f);
    const int tx = tid & 31;
    const int tz = tid >> 5;
    const int r0 = tz * 4;
    const int ybase0 = (YHALO + r0 - 2) * YD + (YHALO + tx - 2);
    const int rbase0 = (RHALO + r0) * RD + (RHALO + tx);

    float yb[8][5];
    #pragma unroll
    for (int i = 0; i < 8; ++i)
        #pragma unroll
        for (int b = 0; b < 5; ++b)
            yb[i][b] = Y[ybase0 + i * YD + b];

    float accR[4] = {0.f,0.f,0.f,0.f}, accG[4] = {0.f,0.f,0.f,0.f};
    float accB[4] = {0.f,0.f,0.f,0.f}, den[4] = {0.f,0.f,0.f,0.f};

    for (int dx = -5; dx <= 5; ++dx) {
        const int yb2 = ybase0 - dx;
        const int rb2 = rbase0 - dx;
        #pragma unroll
        for (int dy = -5; dy <= 5; ++dy) {
            float hs[8];
            #pragma unroll
            for (int i = 0; i < 8; ++i) {
                float s = 0.f;
                #pragma unroll
                for (int b = 0; b < 5; ++b) {
                    float ys = Y[yb2 + (i - dy) * YD + b];
                    float d = yb[i][b] - ys;
                    s = fmaf(d, d, s);
                }
                hs[i] = s;
            }
            float pre[9];
            pre[0] = 0.f;
            #pragma unroll
            for (int i = 0; i < 8; ++i) pre[i + 1] = pre[i] + hs[i];
            #pragma unroll
            for (int rr = 0; rr < 4; ++rr) {
                float box = pre[rr + 5] - pre[rr];
                float w = __expf(-sqrtf(box) * inv_h);
                int s2 = rb2 + (rr - dy) * RD;
                accR[rr] = fmaf(w, RL[s2], accR[rr]);
                accG[rr] = fmaf(w, GL[s2], accG[rr]);
                accB[rr] = fmaf(w, BL[s2], accB[rr]);
                den[rr] += w;
            }
        }
    }

    #pragma unroll
    for (int rr = 0; rr < 4; ++rr) {
        int px = (ty0 + r0 + rr) * IW + tx0 + tx;
        float iw = 1.0f / den[rr];
        out[px]           = fminf(fmaxf(accR[rr] * iw, 0.f), 1.f);
        out[NPX + px]     = fminf(fmaxf(accG[rr] * iw, 0.f), 1.f);
        out[2 * NPX + px] = fminf(fmaxf(accB[rr] * iw, 0.f), 1.f);
    }
}

extern "C" void kernel_launch(void* const* d_in, const int* in_sizes, int n_in,
                              void* d_out, int out_size, void* d_ws, size_t ws_size,
                              hipStream_t stream) {
    const float* rgb   = (const float*)d_in[0];
    const float* sigma = (const float*)d_in[1];
    float* out = (float*)d_out;

    const size_t need = (size_t)NSLICE * NPX * sizeof(float4);
    if (ws_size >= need) {
        float4* ws = (float4*)d_ws;
        dim3 grid(IW / TS, IH / TS, NSLICE);   // 16 x 16 x 4 = 1024 blocks
        nlm_part<<<grid, dim3(256), 0, stream>>>(rgb, sigma, ws);
        nlm_combine<<<dim3(NPX / 256), dim3(256), 0, stream>>>(ws, out);
    } else {
        dim3 grid(IW / TS, IH / TS);
        nlm_mono<<<grid, dim3(256), 0, stream>>>(rgb, sigma, out);
    }
}

// Round 5
// 42.516 us; speedup vs baseline: 2.7818x; 1.3255x over previous
//
#include <hip/hip_runtime.h>
#include <math.h>

#define IH 512
#define IW 512
#define NPX (IH*IW)
#define TS 32
#define YHALO 7              // 5 (search) + 2 (patch)
#define RHALO 5              // search only
#define YD (TS + 2*YHALO)    // 46
#define RD (TS + 2*RHALO)    // 42
#define RSZ (RD*RD)          // 1764
#define NSLICE 4

// fast hardware sqrt: v_sqrt_f32 (~1 ULP). NOTE: __sqrtf is CUDA-only, does
// not exist in HIP (round-4 compile failure).
#define FSQRT(x) __builtin_amdgcn_sqrtf(x)

// ---------------- split compute kernel: one dx-group per blockIdx.z ----------
// Round-3 post-mortem: VALU-issue-bound at ~390 instr/wave-shift (ideal 120).
// This version: rolling 8x5 register window over dy (LDS reads 40->5/shift),
// rebased non-negative LDS offsets (ds_read offset: immediates), merged RGB
// LDS array (one base reg), fast hardware sqrt + __expf.
// NO min-waves clamp (round-2: __launch_bounds__(256,4) caused 0.5GB spill).
__global__ __launch_bounds__(256)
void nlm_part(const float* __restrict__ rgb,
              const float* __restrict__ sigma,
              float4* __restrict__ ws) {
    __shared__ float Y[YD * YD];
    __shared__ float RGBL[3 * RSZ];

    const int tid = threadIdx.x;
    const int tx0 = blockIdx.x * TS;
    const int ty0 = blockIdx.y * TS;
    const int slice = blockIdx.z;

    const float* Rp = rgb;
    const float* Gp = rgb + NPX;
    const float* Bp = rgb + 2 * NPX;

    for (int idx = tid; idx < YD * YD; idx += 256) {
        int a = idx / YD, b = idx - a * YD;
        int gy = (ty0 + a - YHALO) & (IH - 1);
        int gx = (tx0 + b - YHALO) & (IW - 1);
        int g = gy * IW + gx;
        Y[idx] = 0.299f * Rp[g] + 0.587f * Gp[g] + 0.114f * Bp[g];
    }
    for (int idx = tid; idx < RSZ; idx += 256) {
        int a = idx / RD, b = idx - a * RD;
        int gy = (ty0 + a - RHALO) & (IH - 1);
        int gx = (tx0 + b - RHALO) & (IW - 1);
        int g = gy * IW + gx;
        RGBL[idx]           = Rp[g];
        RGBL[RSZ + idx]     = Gp[g];
        RGBL[2 * RSZ + idx] = Bp[g];
    }
    __syncthreads();

    const float minv_h = -1.0f / (fmaxf(sigma[0] * 2.0f, 0.0f) + 1e-6f);

    const int tx = tid & 31;   // column within tile
    const int tz = tid >> 5;   // row strip 0..7
    const int r0 = tz * 4;     // first output row of this strip (tile coords)

    // base-Y patch: rows r0-2..r0+5, cols tx-2..tx+2 (tile coords)
    const int ybase = (YHALO + r0 - 2) * YD + (YHALO + tx - 2);
    float yb[8][5];
    #pragma unroll
    for (int i = 0; i < 8; ++i)
        #pragma unroll
        for (int b = 0; b < 5; ++b)
            yb[i][b] = Y[ybase + i * YD + b];

    float accR[4] = {0.f, 0.f, 0.f, 0.f};
    float accG[4] = {0.f, 0.f, 0.f, 0.f};
    float accB[4] = {0.f, 0.f, 0.f, 0.f};
    float den[4]  = {0.f, 0.f, 0.f, 0.f};

    const int dxlo  = (slice < 3) ? (-5 + 3 * slice) : 4;
    const int dxcnt = (slice < 3) ? 3 : 2;

    for (int u = 0; u < dxcnt; ++u) {
        const int dx = dxlo + u;
        // All LDS offsets below are non-negative compile-time constants
        // relative to these two per-dx bases (fold into ds_read offset:).
        // Window rows (tile coords) span r0-7 .. r0+10 over the dy sweep.
        const int ybd = (YHALO + r0 - 7) * YD + (YHALO + tx - 2 - dx);
        // RGB rows span r0-5 .. r0+8.
        const int rbd = (RHALO + r0 - 5) * RD + (RHALO + tx - dx);

        // rolling window: slot(row) = (row - r0 + 7) & 7, cols tx-2-dx..tx+2-dx
        float win[8][5];
        #pragma unroll
        for (int j = 0; j < 8; ++j)            // rows r0-7 .. r0  (k = 0 state)
            #pragma unroll
            for (int b = 0; b < 5; ++b)
                win[j][b] = Y[ybd + j * YD + b];

        #pragma unroll
        for (int k = 0; k <= 10; ++k) {        // dy = 5 - k
            if (k > 0) {
                // new row r0+k -> slot (k+7)&7, LDS row index j = 7+k
                #pragma unroll
                for (int b = 0; b < 5; ++b)
                    win[(k + 7) & 7][b] = Y[ybd + (7 + k) * YD + b];
            }
            // horizontal 5-tap squared-diff sums; row i uses slot (i+k)&7
            float hs[8];
            #pragma unroll
            for (int i = 0; i < 8; ++i) {
                float s = 0.f;
                #pragma unroll
                for (int b = 0; b < 5; ++b) {
                    float d = yb[i][b] - win[(i + k) & 7][b];
                    s = fmaf(d, d, s);
                }
                hs[i] = s;
            }
            // vertical box via prefix sums
            float pre[9];
            pre[0] = 0.f;
            #pragma unroll
            for (int i = 0; i < 8; ++i) pre[i + 1] = pre[i] + hs[i];
            #pragma unroll
            for (int rr = 0; rr < 4; ++rr) {
                float box = pre[rr + 5] - pre[rr];
                float w = __expf(FSQRT(box) * minv_h);
                const int s2 = rbd + (rr + k) * RD;   // (rr - dy + 5) = rr + k
                accR[rr] = fmaf(w, RGBL[s2], accR[rr]);
                accG[rr] = fmaf(w, RGBL[RSZ + s2], accG[rr]);
                accB[rr] = fmaf(w, RGBL[2 * RSZ + s2], accB[rr]);
                den[rr] += w;
            }
        }
    }

    #pragma unroll
    for (int rr = 0; rr < 4; ++rr) {
        int px = (ty0 + r0 + rr) * IW + tx0 + tx;
        ws[(size_t)slice * NPX + px] =
            make_float4(accR[rr], accG[rr], accB[rr], den[rr]);
    }
}

// ---------------- combine: sum 4 slices, normalize, clip ---------------------
__global__ __launch_bounds__(256)
void nlm_combine(const float4* __restrict__ ws, float* __restrict__ out) {
    int px = blockIdx.x * 256 + threadIdx.x;
    float4 a = ws[px];
    float4 b = ws[NPX + px];
    float4 c = ws[2 * (size_t)NPX + px];
    float4 d = ws[3 * (size_t)NPX + px];
    float r  = a.x + b.x + c.x + d.x;
    float g  = a.y + b.y + c.y + d.y;
    float bl = a.z + b.z + c.z + d.z;
    float w  = a.w + b.w + c.w + d.w;
    float iw = 1.0f / w;
    out[px]               = fminf(fmaxf(r  * iw, 0.f), 1.f);
    out[NPX + px]         = fminf(fmaxf(g  * iw, 0.f), 1.f);
    out[2 * NPX + px]     = fminf(fmaxf(bl * iw, 0.f), 1.f);
}

// ---------------- fallback: monolithic kernel (ws too small) -----------------
__global__ __launch_bounds__(256)
void nlm_mono(const float* __restrict__ rgb,
              const float* __restrict__ sigma,
              float* __restrict__ out) {
    __shared__ float Y[YD * YD];
    __shared__ float RGBL[3 * RSZ];

    const int tid = threadIdx.x;
    const int tx0 = blockIdx.x * TS;
    const int ty0 = blockIdx.y * TS;

    const float* Rp = rgb;
    const float* Gp = rgb + NPX;
    const float* Bp = rgb + 2 * NPX;

    for (int idx = tid; idx < YD * YD; idx += 256) {
        int a = idx / YD, b = idx - a * YD;
        int gy = (ty0 + a - YHALO) & (IH - 1);
        int gx = (tx0 + b - YHALO) & (IW - 1);
        int g = gy * IW + gx;
        Y[idx] = 0.299f * Rp[g] + 0.587f * Gp[g] + 0.114f * Bp[g];
    }
    for (int idx = tid; idx < RSZ; idx += 256) {
        int a = idx / RD, b = idx - a * RD;
        int gy = (ty0 + a - RHALO) & (IH - 1);
        int gx = (tx0 + b - RHALO) & (IW - 1);
        int g = gy * IW + gx;
        RGBL[idx]           = Rp[g];
        RGBL[RSZ + idx]     = Gp[g];
        RGBL[2 * RSZ + idx] = Bp[g];
    }
    __syncthreads();

    const float minv_h = -1.0f / (fmaxf(sigma[0] * 2.0f, 0.0f) + 1e-6f);
    const int tx = tid & 31;
    const int tz = tid >> 5;
    const int r0 = tz * 4;

    const int ybase = (YHALO + r0 - 2) * YD + (YHALO + tx - 2);
    float yb[8][5];
    #pragma unroll
    for (int i = 0; i < 8; ++i)
        #pragma unroll
        for (int b = 0; b < 5; ++b)
            yb[i][b] = Y[ybase + i * YD + b];

    float accR[4] = {0.f,0.f,0.f,0.f}, accG[4] = {0.f,0.f,0.f,0.f};
    float accB[4] = {0.f,0.f,0.f,0.f}, den[4] = {0.f,0.f,0.f,0.f};

    for (int dx = -5; dx <= 5; ++dx) {
        const int ybd = (YHALO + r0 - 7) * YD + (YHALO + tx - 2 - dx);
        const int rbd = (RHALO + r0 - 5) * RD + (RHALO + tx - dx);

        float win[8][5];
        #pragma unroll
        for (int j = 0; j < 8; ++j)
            #pragma unroll
            for (int b = 0; b < 5; ++b)
                win[j][b] = Y[ybd + j * YD + b];

        #pragma unroll
        for (int k = 0; k <= 10; ++k) {
            if (k > 0) {
                #pragma unroll
                for (int b = 0; b < 5; ++b)
                    win[(k + 7) & 7][b] = Y[ybd + (7 + k) * YD + b];
            }
            float hs[8];
            #pragma unroll
            for (int i = 0; i < 8; ++i) {
                float s = 0.f;
                #pragma unroll
                for (int b = 0; b < 5; ++b) {
                    float d = yb[i][b] - win[(i + k) & 7][b];
                    s = fmaf(d, d, s);
                }
                hs[i] = s;
            }
            float pre[9];
            pre[0] = 0.f;
            #pragma unroll
            for (int i = 0; i < 8; ++i) pre[i + 1] = pre[i] + hs[i];
            #pragma unroll
            for (int rr = 0; rr < 4; ++rr) {
                float box = pre[rr + 5] - pre[rr];
                float w = __expf(FSQRT(box) * minv_h);
                const int s2 = rbd + (rr + k) * RD;
                accR[rr] = fmaf(w, RGBL[s2], accR[rr]);
                accG[rr] = fmaf(w, RGBL[RSZ + s2], accG[rr]);
                accB[rr] = fmaf(w, RGBL[2 * RSZ + s2], accB[rr]);
                den[rr] += w;
            }
        }
    }

    #pragma unroll
    for (int rr = 0; rr < 4; ++rr) {
        int px = (ty0 + r0 + rr) * IW + tx0 + tx;
        float iw = 1.0f / den[rr];
        out[px]           = fminf(fmaxf(accR[rr] * iw, 0.f), 1.f);
        out[NPX + px]     = fminf(fmaxf(accG[rr] * iw, 0.f), 1.f);
        out[2 * NPX + px] = fminf(fmaxf(accB[rr] * iw, 0.f), 1.f);
    }
}

extern "C" void kernel_launch(void* const* d_in, const int* in_sizes, int n_in,
                              void* d_out, int out_size, void* d_ws, size_t ws_size,
                              hipStream_t stream) {
    const float* rgb   = (const float*)d_in[0];
    const float* sigma = (const float*)d_in[1];
    float* out = (float*)d_out;

    const size_t need = (size_t)NSLICE * NPX * sizeof(float4);
    if (ws_size >= need) {
        float4* ws = (float4*)d_ws;
        dim3 grid(IW / TS, IH / TS, NSLICE);   // 16 x 16 x 4 = 1024 blocks
        nlm_part<<<grid, dim3(256), 0, stream>>>(rgb, sigma, ws);
        nlm_combine<<<dim3(NPX / 256), dim3(256), 0, stream>>>(ws, out);
    } else {
        dim3 grid(IW / TS, IH / TS);
        nlm_mono<<<grid, dim3(256), 0, stream>>>(rgb, sigma, out);
    }
}